// Round 4
// baseline (631.442 us; speedup 1.0000x reference)
//
#include <hip/hip_runtime.h>
#include <hip/hip_bf16.h>

#define B_ROWS 16384
#define D_DIM  3072
#define H_DIM  128
#define O_DIM  10
#define E_NUM  8

typedef __hip_bfloat16 bf16;
typedef __attribute__((ext_vector_type(8))) short short8;   // 8 bf16 = 4 VGPRs (MFMA A/B frag)
typedef __attribute__((ext_vector_type(4))) float floatx4;  // MFMA C/D frag

// async global->LDS 16B: wave-uniform LDS base, per-lane global addr (m97 pattern)
__device__ __forceinline__ void async_load16(const bf16* g, bf16* l) {
    __builtin_amdgcn_global_load_lds(
        (const __attribute__((address_space(1))) unsigned int*)(const void*)g,
        (__attribute__((address_space(3))) unsigned int*)(void*)l, 16, 0, 0);
}

// ---------------------------------------------------------------------------
// K0: transpose+convert  in[e][R][C] fp32  ->  out[e][C][R] bf16
// ---------------------------------------------------------------------------
__global__ void transpose_bf16_kernel(const float* __restrict__ in,
                                      bf16* __restrict__ out, int R, int C) {
    int e = blockIdx.z;
    const float* inp = in + (size_t)e * R * C;
    bf16* outp = out + (size_t)e * R * C;
    __shared__ float tile[32][33];
    int tx = threadIdx.x;   // 0..31
    int ty = threadIdx.y;   // 0..7
    int r0 = blockIdx.x * 32, c0 = blockIdx.y * 32;
#pragma unroll
    for (int i = 0; i < 4; i++)
        tile[ty + i * 8][tx] = inp[(size_t)(r0 + ty + i * 8) * C + c0 + tx];
    __syncthreads();
#pragma unroll
    for (int i = 0; i < 4; i++)
        outp[(size_t)(c0 + ty + i * 8) * R + r0 + tx] =
            __float2bfloat16(tile[tx][ty + i * 8]);
}

// ---------------------------------------------------------------------------
// K0b: reorder gate_w into lane-major layout so gate_kernel's g-loads are
// coalesced.  gwr[j*2048 + k*256 + l*4 + c] = gw_flat[(j*256 + l*4)*8 + k*4 + c]
// ---------------------------------------------------------------------------
__global__ __launch_bounds__(256) void gate_w_reorder_kernel(
    const float* __restrict__ gw, float* __restrict__ gwr)
{
    int tid = blockIdx.x * 256 + threadIdx.x;        // one float4 each, 24576 total
    int j = tid >> 9, rem = tid & 511;
    int k = rem >> 6, l = rem & 63;
    float4 v = *(const float4*)&gw[(size_t)(j * 256 + l * 4) * 8 + k * 4];
    *(float4*)&gwr[(size_t)tid * 4] = v;
}

// ---------------------------------------------------------------------------
// K1: gate v8. v7 was still latency-bound on x reads: load->use distance of
// one j-body (~100-300cy) << ~900cy HBM latency, and launch_bounds(256,4)
// capped waves. Now: depth-2 x prefetch + launch_bounds(256,8) (VGPR 40
// permits 8 waves/SIMD; grid = exactly 8 blocks/CU). Score math unchanged.
// ---------------------------------------------------------------------------
__global__ __launch_bounds__(256, 8) void gate_kernel(
    const float* __restrict__ x, const float* __restrict__ gwr,
    const float* __restrict__ gate_b, bf16* __restrict__ x_bf16,
    int* __restrict__ rowlist, float* __restrict__ wlist, int* __restrict__ gcnt)
{
    __shared__ int   eidx[8][2];
    __shared__ float ew[8][2];
    __shared__ int   lcnt[E_NUM], gbase[E_NUM];

    int t = threadIdx.x, w = t >> 6, l = t & 63;
    int rowblk = blockIdx.x * 8;
    int r0 = rowblk + w * 2;

    float4 accA[2], accB[2];   // experts 0-3 / 4-7 per row
#pragma unroll
    for (int r = 0; r < 2; r++) {
        accA[r] = (float4){0.f, 0.f, 0.f, 0.f};
        accB[r] = (float4){0.f, 0.f, 0.f, 0.f};
    }

    const float* xr0 = x + (size_t)r0 * D_DIM;
    const float* xr1 = x + (size_t)(r0 + 1) * D_DIM;
    int dl = l * 4;

    float4 xv[2], xn[2];                     // depth-2 prefetch ring
    xv[0] = *(const float4*)&xr0[dl];
    xv[1] = *(const float4*)&xr1[dl];
    xn[0] = *(const float4*)&xr0[dl + 256];
    xn[1] = *(const float4*)&xr1[dl + 256];

#pragma unroll 1
    for (int j = 0; j < 12; j++) {
        int dd = j * 256 + dl;                      // lane's 4 d-rows
        const float4* gwp = (const float4*)(gwr + (size_t)j * 2048 + dl);
        float4 g[8];                                // g[k] = old flat[dd*8+k*4..+3]
#pragma unroll
        for (int k = 0; k < 8; k++) g[k] = gwp[k * 64];   // k*256 floats apart
        float4 xm0 = xn[0], xm1 = xn[1];
        if (j < 10) {                               // prefetch j+2's x rows
            xm0 = *(const float4*)&xr0[dd + 512];
            xm1 = *(const float4*)&xr1[dd + 512];
        }
#pragma unroll
        for (int r = 0; r < 2; r++) {
            float4 xvv = xv[r];
            size_t xi = (size_t)(r0 + r) * D_DIM + dd;
            union { bf16 h[4]; uint2 v; } pk;
            pk.h[0] = __float2bfloat16(xvv.x);
            pk.h[1] = __float2bfloat16(xvv.y);
            pk.h[2] = __float2bfloat16(xvv.z);
            pk.h[3] = __float2bfloat16(xvv.w);
            *(uint2*)&x_bf16[xi] = pk.v;
            accA[r].x += xvv.x * g[0].x + xvv.y * g[2].x + xvv.z * g[4].x + xvv.w * g[6].x;
            accA[r].y += xvv.x * g[0].y + xvv.y * g[2].y + xvv.z * g[4].y + xvv.w * g[6].y;
            accA[r].z += xvv.x * g[0].z + xvv.y * g[2].z + xvv.z * g[4].z + xvv.w * g[6].z;
            accA[r].w += xvv.x * g[0].w + xvv.y * g[2].w + xvv.z * g[4].w + xvv.w * g[6].w;
            accB[r].x += xvv.x * g[1].x + xvv.y * g[3].x + xvv.z * g[5].x + xvv.w * g[7].x;
            accB[r].y += xvv.x * g[1].y + xvv.y * g[3].y + xvv.z * g[5].y + xvv.w * g[7].y;
            accB[r].z += xvv.x * g[1].z + xvv.y * g[3].z + xvv.z * g[5].z + xvv.w * g[7].z;
            accB[r].w += xvv.x * g[1].w + xvv.y * g[3].w + xvv.z * g[5].w + xvv.w * g[7].w;
        }
        xv[0] = xn[0]; xv[1] = xn[1];
        xn[0] = xm0;   xn[1] = xm1;
    }

    // butterfly reduce across 64 lanes
#pragma unroll
    for (int r = 0; r < 2; r++) {
        float s[8] = {accA[r].x, accA[r].y, accA[r].z, accA[r].w,
                      accB[r].x, accB[r].y, accB[r].z, accB[r].w};
#pragma unroll
        for (int e = 0; e < 8; e++) {
            float v = s[e];
#pragma unroll
            for (int off = 1; off < 64; off <<= 1) v += __shfl_xor(v, off, 64);
            s[e] = v;
        }
        accA[r] = (float4){s[0], s[1], s[2], s[3]};
        accB[r] = (float4){s[4], s[5], s[6], s[7]};
    }

    if (l == 0) {
#pragma unroll
        for (int r = 0; r < 2; r++) {
            float s[8] = {accA[r].x, accA[r].y, accA[r].z, accA[r].w,
                          accB[r].x, accB[r].y, accB[r].z, accB[r].w};
#pragma unroll
            for (int e = 0; e < 8; e++) s[e] += gate_b[e];
            // top-1 / top-2, strict > keeps lowest index on ties (lax.top_k)
            int i1 = 0; float m1 = s[0];
#pragma unroll
            for (int e = 1; e < 8; e++) if (s[e] > m1) { m1 = s[e]; i1 = e; }
            int i2 = -1; float m2 = -1e30f;
#pragma unroll
            for (int e = 0; e < 8; e++)
                if (e != i1 && s[e] > m2) { m2 = s[e]; i2 = e; }
            float S = 0.0f;
#pragma unroll
            for (int e = 0; e < 8; e++) S += expf(s[e] - m1);
            float p1 = expf(s[i1] - m1) / S;
            float p2 = expf(m2 - m1) / S;
            float denom = p1 + p2 + 1e-8f;
            eidx[w * 2 + r][0] = i1; ew[w * 2 + r][0] = p1 / denom;
            eidx[w * 2 + r][1] = i2; ew[w * 2 + r][1] = p2 / denom;
        }
    }
    __syncthreads();
    if (t < 8) lcnt[t] = 0;
    __syncthreads();
    int my_e = 0, my_lp = 0, my_rl = 0, my_sl = 0;
    if (t < 16) {
        my_rl = t >> 1; my_sl = t & 1;
        my_e = eidx[my_rl][my_sl];
        my_lp = atomicAdd(&lcnt[my_e], 1);
    }
    __syncthreads();
    if (t < 8) gbase[t] = atomicAdd(&gcnt[t], lcnt[t]);
    __syncthreads();
    if (t < 16) {
        int pos = gbase[my_e] + my_lp;
        rowlist[my_e * B_ROWS + pos] = rowblk + my_rl;
        wlist[my_e * B_ROWS + pos]   = ew[my_rl][my_sl];
    }
}

// ---------------------------------------------------------------------------
// K2: FUSED expert MLP. Phase 1 = gemm1 v2 (m97 structure, BM=128 BN=128
// BK=64, 8 waves, global_load_lds dbuf, both-sides XOR swizzle). Phase 2:
// the block's h1 tile (128 rows x all 128 cols) is complete, so gemm2c is
// inlined: reuse the 64KB phase-1 LDS (aliased smem) for h1s/w2s/w3ts, run
// h2 = relu(h1@w2+b2) with 8 waves (wave-tile 32x64), then the y-tile MFMA
// and guarded atomic scatter. Eliminates the h1buf global round-trip
// (17MB), one kernel launch, and halves w2 staging. Numerics identical:
// h1/h2 pass through the same bf16 rounding as the old buffer round-trip.
// 1D grid, e = bid&7: XCD i serves only expert i -> w1t_e/w2t_e L2-resident.
// ---------------------------------------------------------------------------
__global__ __launch_bounds__(512, 4) void moe_fused_kernel(
    const bf16* __restrict__ xb, const bf16* __restrict__ w1t,
    const float* __restrict__ b1, const bf16* __restrict__ w2t,
    const float* __restrict__ b2, const float* __restrict__ w3,
    const float* __restrict__ b3, const int* __restrict__ rowlist,
    const float* __restrict__ wlist, const int* __restrict__ gcnt,
    float* __restrict__ y)
{
    int e  = blockIdx.x & 7;
    int bx = blockIdx.x >> 3;
    int cnt = gcnt[e];
    int t0 = bx * 128;
    if (t0 >= cnt) return;
    int mcnt = cnt - t0; if (mcnt > 128) mcnt = 128;

    // aliased LDS: phase1 Ab[2][128*64] @0 (32KB) + Bb[2][128*64] @32768;
    // phase2 h1s[128][136] @0, w2s[128][136] @34816, w3ts[16][136] @69632
    __shared__ __align__(16) char smem[73984];
    __shared__ int   rows_s[128];
    __shared__ float wts[128];
    __shared__ float b1s[H_DIM], b2s[H_DIM], b3s[O_DIM];

    bf16* AbP = (bf16*)smem;              // phase1 A
    bf16* BbP = (bf16*)(smem + 32768);    // phase1 B

    int t = threadIdx.x, w = t >> 6, l = t & 63;
    if (t < 128) {
        int rr = (t < mcnt) ? t : (mcnt - 1);
        rows_s[t] = rowlist[e * B_ROWS + t0 + rr];
        wts[t]    = wlist[e * B_ROWS + t0 + rr];
    } else if (t < 256) {
        b1s[t - 128] = b1[e * H_DIM + (t - 128)];
    } else if (t < 384) {
        b2s[t - 256] = b2[e * H_DIM + (t - 256)];
    } else if (t < 384 + O_DIM) {
        b3s[t - 384] = b3[e * O_DIM + (t - 384)];
    }
    __syncthreads();

    const bf16* w1base = w1t + (size_t)e * H_DIM * D_DIM;
    // staging geometry: wave w fills segments 2w,2w+1 (1KB each) of A and B.
    // seg s, lane l -> row s*8 + (l>>3), block-in-row = l&7, source chunk
    // = (l&7) ^ ((l>>3)&7)  (XOR pre-swizzle; 8-lane group = one row's 128B)
    int sub = l >> 3;
    int blk = (l & 7) ^ sub;
    const bf16* aP0 = xb + (size_t)rows_s[w * 16 + sub]     * D_DIM + blk * 8;
    const bf16* aP1 = xb + (size_t)rows_s[w * 16 + 8 + sub] * D_DIM + blk * 8;
    const bf16* bP0 = w1base + (size_t)(w * 16 + sub)     * D_DIM + blk * 8;
    const bf16* bP1 = w1base + (size_t)(w * 16 + 8 + sub) * D_DIM + blk * 8;
    bf16* ldsA0 = AbP + (2 * w) * 512, *ldsA1 = AbP + (2 * w + 1) * 512;
    bf16* ldsB0 = BbP + (2 * w) * 512, *ldsB1 = BbP + (2 * w + 1) * 512;

    auto stage = [&](int bs, int kb) {
        int k0 = kb * 64;
        int boff = bs * 128 * 64;
        async_load16(aP0 + k0, ldsA0 + boff);
        async_load16(aP1 + k0, ldsA1 + boff);
        async_load16(bP0 + k0, ldsB0 + boff);
        async_load16(bP1 + k0, ldsB1 + boff);
    };

    int wr = w & 3, wc = w >> 2;                 // wave tile: rows wr*32, cols wc*64
    floatx4 acc[2][4];
#pragma unroll
    for (int mi = 0; mi < 2; mi++)
#pragma unroll
        for (int ni = 0; ni < 4; ni++) acc[mi][ni] = (floatx4){0.f, 0.f, 0.f, 0.f};

    stage(0, 0);

    const int NKB = D_DIM / 64;   // 48
    for (int kb = 0; kb < NKB; kb++) {
        int bs = kb & 1;
        __syncthreads();                          // drains stage(bs); prev reads done
        if (kb + 1 < NKB) stage(bs ^ 1, kb + 1);  // in flight across MFMA phase
#pragma unroll
        for (int kc8 = 0; kc8 < 8; kc8 += 4) {
            int c = kc8 + (l >> 4);
            int swz = (c ^ (l & 7)) * 8;          // R&7 == C&7 == l&7
            short8 af[2], bfr[4];
#pragma unroll
            for (int mi = 0; mi < 2; mi++) {
                int R = wr * 32 + mi * 16 + (l & 15);
                af[mi] = *(const short8*)&AbP[bs * 8192 + R * 64 + swz];
            }
#pragma unroll
            for (int ni = 0; ni < 4; ni++) {
                int C = wc * 64 + ni * 16 + (l & 15);
                bfr[ni] = *(const short8*)&BbP[bs * 8192 + C * 64 + swz];
            }
#pragma unroll
            for (int mi = 0; mi < 2; mi++)
#pragma unroll
                for (int ni = 0; ni < 4; ni++)
                    acc[mi][ni] = __builtin_amdgcn_mfma_f32_16x16x32_bf16(
                        af[mi], bfr[ni], acc[mi][ni], 0, 0, 0);
        }
    }
    __syncthreads();   // all phase-1 LDS reads done; no loads pending -> reuse

    // ---- phase 2: h1 tile -> LDS, stage w2/w3, h2 GEMM, y GEMM, scatter ----
    bf16* h1s  = (bf16*)smem;             // [128][136]  (reused later as h2s)
    bf16* w2s  = (bf16*)(smem + 34816);   // [128][136]
    bf16* w3ts = (bf16*)(smem + 69632);   // [16][136]

    // h1 = relu(acc + b1): write each wave's 32x64 tile into LDS
    // (D row = (l>>4)*4 + reg, col = l&15; rows >= mcnt are dup-valid)
#pragma unroll
    for (int mi = 0; mi < 2; mi++)
#pragma unroll
        for (int r = 0; r < 4; r++) {
            int row = wr * 32 + mi * 16 + (l >> 4) * 4 + r;
#pragma unroll
            for (int ni = 0; ni < 4; ni++) {
                int col = wc * 64 + ni * 16 + (l & 15);
                h1s[row * 136 + col] =
                    __float2bfloat16(fmaxf(acc[mi][ni][r] + b1s[col], 0.0f));
            }
        }

    // stage w2 (128x128 bf16) and transposed zero-padded w3 (16x128)
    {
        const bf16* w2base = w2t + (size_t)e * H_DIM * H_DIM;
#pragma unroll
        for (int k = 0; k < 4; k++) {
            int si = t + 512 * k;                   // 0..2047 chunks of 16B
            *(uint4*)&w2s[(si >> 4) * 136 + (si & 15) * 8] =
                *(const uint4*)(w2base + (size_t)(si >> 4) * H_DIM + (si & 15) * 8);
        }
        for (int idx = t; idx < H_DIM * O_DIM; idx += 512)
            w3ts[(idx % 10) * 136 + idx / 10] =
                __float2bfloat16(w3[(size_t)e * H_DIM * O_DIM + idx]);
        for (int idx = t; idx < 6 * 128; idx += 512)
            w3ts[(10 + idx / 128) * 136 + (idx % 128)] = __float2bfloat16(0.0f);
    }
    __syncthreads();

    // h2 = relu(h1 @ w2 + b2), 8 waves, wave-tile 32x64, K=128
    int mb = wr * 32, nb = wc * 64;
    floatx4 acc2[2][4];
#pragma unroll
    for (int mi = 0; mi < 2; mi++)
#pragma unroll
        for (int ni = 0; ni < 4; ni++) acc2[mi][ni] = (floatx4){0.f, 0.f, 0.f, 0.f};
#pragma unroll
    for (int kc = 0; kc < 128; kc += 32) {
        short8 af[2], bfr[4];
#pragma unroll
        for (int mi = 0; mi < 2; mi++)
            af[mi] = *(const short8*)&h1s[(mb + mi * 16 + (l & 15)) * 136 + kc + (l >> 4) * 8];
#pragma unroll
        for (int ni = 0; ni < 4; ni++)
            bfr[ni] = *(const short8*)&w2s[(nb + ni * 16 + (l & 15)) * 136 + kc + (l >> 4) * 8];
#pragma unroll
        for (int mi = 0; mi < 2; mi++)
#pragma unroll
            for (int ni = 0; ni < 4; ni++)
                acc2[mi][ni] = __builtin_amdgcn_mfma_f32_16x16x32_bf16(
                    af[mi], bfr[ni], acc2[mi][ni], 0, 0, 0);
    }
    __syncthreads();   // all reads of h1s done; reuse as h2s

    bf16* h2s = h1s;
#pragma unroll
    for (int mi = 0; mi < 2; mi++)
#pragma unroll
        for (int r = 0; r < 4; r++) {
            int row = mb + mi * 16 + (l >> 4) * 4 + r;
#pragma unroll
            for (int ni = 0; ni < 4; ni++) {
                int col = nb + ni * 16 + (l & 15);
                h2s[row * 136 + col] =
                    __float2bfloat16(fmaxf(acc2[mi][ni][r] + b2s[col], 0.0f));
            }
        }
    __syncthreads();

    // y tile via MFMA (wave w -> rows w*16..w*16+15), K=128
    floatx4 acc3 = (floatx4){0.f, 0.f, 0.f, 0.f};
    int m3 = w * 16;
#pragma unroll
    for (int kc = 0; kc < 128; kc += 32) {
        short8 af  = *(const short8*)&h2s[(m3 + (l & 15)) * 136 + kc + (l >> 4) * 8];
        short8 bf3 = *(const short8*)&w3ts[(l & 15) * 136 + kc + (l >> 4) * 8];
        acc3 = __builtin_amdgcn_mfma_f32_16x16x32_bf16(af, bf3, acc3, 0, 0, 0);
    }
    int col = l & 15;
    if (col < O_DIM) {
#pragma unroll
        for (int r = 0; r < 4; r++) {
            int row = m3 + (l >> 4) * 4 + r;
            if (row < mcnt)
                atomicAdd(&y[(size_t)rows_s[row] * O_DIM + col],
                          wts[row] * (acc3[r] + b3s[col]));
        }
    }
}

// ---------------------------------------------------------------------------
extern "C" void kernel_launch(void* const* d_in, const int* in_sizes, int n_in,
                              void* d_out, int out_size, void* d_ws, size_t ws_size,
                              hipStream_t stream) {
    (void)in_sizes; (void)n_in; (void)ws_size;
    const float* x      = (const float*)d_in[0];
    const float* gate_w = (const float*)d_in[1];
    const float* gate_b = (const float*)d_in[2];
    const float* w1     = (const float*)d_in[3];
    const float* b1     = (const float*)d_in[4];
    const float* w2     = (const float*)d_in[5];
    const float* b2     = (const float*)d_in[6];
    const float* w3     = (const float*)d_in[7];
    const float* b3     = (const float*)d_in[8];
    float* y = (float*)d_out;

    char* ws = (char*)d_ws;
    size_t off = 0;
    auto alloc = [&](size_t bytes) {
        void* p = ws + off;
        off = (off + bytes + 255) & ~(size_t)255;
        return p;
    };
    bf16*  x_bf16  = (bf16*)alloc((size_t)B_ROWS * D_DIM * 2);            // 100.7 MB
    bf16*  w1t     = (bf16*)alloc((size_t)E_NUM * H_DIM * D_DIM * 2);     // 6.3 MB
    bf16*  w2t     = (bf16*)alloc((size_t)E_NUM * H_DIM * H_DIM * 2);     // 0.26 MB
    float* gwr     = (float*)alloc((size_t)D_DIM * E_NUM * 4);            // 393 KB
    int*   rowlist = (int*)alloc((size_t)E_NUM * B_ROWS * 4);
    float* wlist   = (float*)alloc((size_t)E_NUM * B_ROWS * 4);
    int*   gcnt    = (int*)alloc(64);

    hipMemsetAsync(d_out, 0, (size_t)out_size * sizeof(float), stream);
    hipMemsetAsync(gcnt, 0, 64, stream);

    gate_w_reorder_kernel<<<D_DIM * E_NUM / 4 / 256, 256, 0, stream>>>(gate_w, gwr);
    transpose_bf16_kernel<<<dim3(D_DIM / 32, H_DIM / 32, E_NUM), dim3(32, 8), 0, stream>>>(
        w1, w1t, D_DIM, H_DIM);
    transpose_bf16_kernel<<<dim3(H_DIM / 32, H_DIM / 32, E_NUM), dim3(32, 8), 0, stream>>>(
        w2, w2t, H_DIM, H_DIM);
    gate_kernel<<<B_ROWS / 8, 256, 0, stream>>>(x, gwr, gate_b, x_bf16,
                                                rowlist, wlist, gcnt);
    moe_fused_kernel<<<(B_ROWS / 128) * E_NUM, 512, 0, stream>>>(
        x_bf16, w1t, b1, w2t, b2, w3, b3, rowlist, wlist, gcnt, y);
}

// Round 5
// 416.672 us; speedup vs baseline: 1.5154x; 1.5154x over previous
//
#include <hip/hip_runtime.h>
#include <hip/hip_bf16.h>

#define B_ROWS 16384
#define D_DIM  3072
#define H_DIM  128
#define O_DIM  10
#define E_NUM  8

typedef __hip_bfloat16 bf16;
typedef __attribute__((ext_vector_type(8))) short short8;   // 8 bf16 = 4 VGPRs (MFMA A/B frag)
typedef __attribute__((ext_vector_type(4))) float floatx4;  // MFMA C/D frag

// async global->LDS 16B: wave-uniform LDS base, per-lane global addr (m97 pattern)
__device__ __forceinline__ void async_load16(const bf16* g, bf16* l) {
    __builtin_amdgcn_global_load_lds(
        (const __attribute__((address_space(1))) unsigned int*)(const void*)g,
        (__attribute__((address_space(3))) unsigned int*)(void*)l, 16, 0, 0);
}

// ---------------------------------------------------------------------------
// K0: transpose+convert  in[e][R][C] fp32  ->  out[e][C][R] bf16
// ---------------------------------------------------------------------------
__global__ void transpose_bf16_kernel(const float* __restrict__ in,
                                      bf16* __restrict__ out, int R, int C) {
    int e = blockIdx.z;
    const float* inp = in + (size_t)e * R * C;
    bf16* outp = out + (size_t)e * R * C;
    __shared__ float tile[32][33];
    int tx = threadIdx.x;   // 0..31
    int ty = threadIdx.y;   // 0..7
    int r0 = blockIdx.x * 32, c0 = blockIdx.y * 32;
#pragma unroll
    for (int i = 0; i < 4; i++)
        tile[ty + i * 8][tx] = inp[(size_t)(r0 + ty + i * 8) * C + c0 + tx];
    __syncthreads();
#pragma unroll
    for (int i = 0; i < 4; i++)
        outp[(size_t)(c0 + ty + i * 8) * R + r0 + tx] =
            __float2bfloat16(tile[tx][ty + i * 8]);
}

// ---------------------------------------------------------------------------
// K0b: reorder gate_w into lane-major layout so gate_kernel's g-loads are
// coalesced.  gwr[j*2048 + k*256 + l*4 + c] = gw_flat[(j*256 + l*4)*8 + k*4 + c]
// ---------------------------------------------------------------------------
__global__ __launch_bounds__(256) void gate_w_reorder_kernel(
    const float* __restrict__ gw, float* __restrict__ gwr)
{
    int tid = blockIdx.x * 256 + threadIdx.x;        // one float4 each, 24576 total
    int j = tid >> 9, rem = tid & 511;
    int k = rem >> 6, l = rem & 63;
    float4 v = *(const float4*)&gw[(size_t)(j * 256 + l * 4) * 8 + k * 4];
    *(float4*)&gwr[(size_t)tid * 4] = v;
}

// ---------------------------------------------------------------------------
// K1: gate v7 (REVERT of v8). v8's launch_bounds(256,8) capped VGPR at 32
// vs a ~80-reg live set -> scratch spills (WRITE_SIZE 99->650 MB, 333us).
// v7: launch_bounds(256,4), depth-1 prefetch, 40 VGPR, no spills (<118us).
// ---------------------------------------------------------------------------
__global__ __launch_bounds__(256, 4) void gate_kernel(
    const float* __restrict__ x, const float* __restrict__ gwr,
    const float* __restrict__ gate_b, bf16* __restrict__ x_bf16,
    int* __restrict__ rowlist, float* __restrict__ wlist, int* __restrict__ gcnt)
{
    __shared__ int   eidx[8][2];
    __shared__ float ew[8][2];
    __shared__ int   lcnt[E_NUM], gbase[E_NUM];

    int t = threadIdx.x, w = t >> 6, l = t & 63;
    int rowblk = blockIdx.x * 8;
    int r0 = rowblk + w * 2;

    float4 accA[2], accB[2];   // experts 0-3 / 4-7 per row
#pragma unroll
    for (int r = 0; r < 2; r++) {
        accA[r] = (float4){0.f, 0.f, 0.f, 0.f};
        accB[r] = (float4){0.f, 0.f, 0.f, 0.f};
    }

    const float* xr0 = x + (size_t)r0 * D_DIM;
    const float* xr1 = x + (size_t)(r0 + 1) * D_DIM;
    int dl = l * 4;

    float4 xv[2], xn[2];
    xv[0] = *(const float4*)&xr0[dl];
    xv[1] = *(const float4*)&xr1[dl];

#pragma unroll 1
    for (int j = 0; j < 12; j++) {
        int dd = j * 256 + dl;                      // lane's 4 d-rows
        const float4* gwp = (const float4*)(gwr + (size_t)j * 2048 + dl);
        float4 g[8];                                // g[k] = old flat[dd*8+k*4..+3]
#pragma unroll
        for (int k = 0; k < 8; k++) g[k] = gwp[k * 64];   // k*256 floats apart
        if (j < 11) {                               // prefetch next j's x rows
            xn[0] = *(const float4*)&xr0[dd + 256];
            xn[1] = *(const float4*)&xr1[dd + 256];
        }
#pragma unroll
        for (int r = 0; r < 2; r++) {
            float4 xvv = xv[r];
            size_t xi = (size_t)(r0 + r) * D_DIM + dd;
            union { bf16 h[4]; uint2 v; } pk;
            pk.h[0] = __float2bfloat16(xvv.x);
            pk.h[1] = __float2bfloat16(xvv.y);
            pk.h[2] = __float2bfloat16(xvv.z);
            pk.h[3] = __float2bfloat16(xvv.w);
            *(uint2*)&x_bf16[xi] = pk.v;
            accA[r].x += xvv.x * g[0].x + xvv.y * g[2].x + xvv.z * g[4].x + xvv.w * g[6].x;
            accA[r].y += xvv.x * g[0].y + xvv.y * g[2].y + xvv.z * g[4].y + xvv.w * g[6].y;
            accA[r].z += xvv.x * g[0].z + xvv.y * g[2].z + xvv.z * g[4].z + xvv.w * g[6].z;
            accA[r].w += xvv.x * g[0].w + xvv.y * g[2].w + xvv.z * g[4].w + xvv.w * g[6].w;
            accB[r].x += xvv.x * g[1].x + xvv.y * g[3].x + xvv.z * g[5].x + xvv.w * g[7].x;
            accB[r].y += xvv.x * g[1].y + xvv.y * g[3].y + xvv.z * g[5].y + xvv.w * g[7].y;
            accB[r].z += xvv.x * g[1].z + xvv.y * g[3].z + xvv.z * g[5].z + xvv.w * g[7].z;
            accB[r].w += xvv.x * g[1].w + xvv.y * g[3].w + xvv.z * g[5].w + xvv.w * g[7].w;
        }
        xv[0] = xn[0];
        xv[1] = xn[1];
    }

    // butterfly reduce across 64 lanes
#pragma unroll
    for (int r = 0; r < 2; r++) {
        float s[8] = {accA[r].x, accA[r].y, accA[r].z, accA[r].w,
                      accB[r].x, accB[r].y, accB[r].z, accB[r].w};
#pragma unroll
        for (int e = 0; e < 8; e++) {
            float v = s[e];
#pragma unroll
            for (int off = 1; off < 64; off <<= 1) v += __shfl_xor(v, off, 64);
            s[e] = v;
        }
        accA[r] = (float4){s[0], s[1], s[2], s[3]};
        accB[r] = (float4){s[4], s[5], s[6], s[7]};
    }

    if (l == 0) {
#pragma unroll
        for (int r = 0; r < 2; r++) {
            float s[8] = {accA[r].x, accA[r].y, accA[r].z, accA[r].w,
                          accB[r].x, accB[r].y, accB[r].z, accB[r].w};
#pragma unroll
            for (int e = 0; e < 8; e++) s[e] += gate_b[e];
            // top-1 / top-2, strict > keeps lowest index on ties (lax.top_k)
            int i1 = 0; float m1 = s[0];
#pragma unroll
            for (int e = 1; e < 8; e++) if (s[e] > m1) { m1 = s[e]; i1 = e; }
            int i2 = -1; float m2 = -1e30f;
#pragma unroll
            for (int e = 0; e < 8; e++)
                if (e != i1 && s[e] > m2) { m2 = s[e]; i2 = e; }
            float S = 0.0f;
#pragma unroll
            for (int e = 0; e < 8; e++) S += expf(s[e] - m1);
            float p1 = expf(s[i1] - m1) / S;
            float p2 = expf(m2 - m1) / S;
            float denom = p1 + p2 + 1e-8f;
            eidx[w * 2 + r][0] = i1; ew[w * 2 + r][0] = p1 / denom;
            eidx[w * 2 + r][1] = i2; ew[w * 2 + r][1] = p2 / denom;
        }
    }
    __syncthreads();
    if (t < 8) lcnt[t] = 0;
    __syncthreads();
    int my_e = 0, my_lp = 0, my_rl = 0, my_sl = 0;
    if (t < 16) {
        my_rl = t >> 1; my_sl = t & 1;
        my_e = eidx[my_rl][my_sl];
        my_lp = atomicAdd(&lcnt[my_e], 1);
    }
    __syncthreads();
    if (t < 8) gbase[t] = atomicAdd(&gcnt[t], lcnt[t]);
    __syncthreads();
    if (t < 16) {
        int pos = gbase[my_e] + my_lp;
        rowlist[my_e * B_ROWS + pos] = rowblk + my_rl;
        wlist[my_e * B_ROWS + pos]   = ew[my_rl][my_sl];
    }
}

// ---------------------------------------------------------------------------
// K2: FUSED expert MLP (unchanged from round 4). Phase 1 = m97-structure
// gemm1 (BM=128 BN=128 BK=64, 8 waves, global_load_lds dbuf, both-sides XOR
// swizzle). Phase 2: reuse LDS for h1s/w2s/w3ts; h2 GEMM (8 waves, 32x64);
// y-tile MFMA + guarded atomic scatter. e = bid&7 -> expert-per-XCD affinity.
// ---------------------------------------------------------------------------
__global__ __launch_bounds__(512, 4) void moe_fused_kernel(
    const bf16* __restrict__ xb, const bf16* __restrict__ w1t,
    const float* __restrict__ b1, const bf16* __restrict__ w2t,
    const float* __restrict__ b2, const float* __restrict__ w3,
    const float* __restrict__ b3, const int* __restrict__ rowlist,
    const float* __restrict__ wlist, const int* __restrict__ gcnt,
    float* __restrict__ y)
{
    int e  = blockIdx.x & 7;
    int bx = blockIdx.x >> 3;
    int cnt = gcnt[e];
    int t0 = bx * 128;
    if (t0 >= cnt) return;
    int mcnt = cnt - t0; if (mcnt > 128) mcnt = 128;

    // aliased LDS: phase1 Ab[2][128*64] @0 (32KB) + Bb[2][128*64] @32768;
    // phase2 h1s[128][136] @0, w2s[128][136] @34816, w3ts[16][136] @69632
    __shared__ __align__(16) char smem[73984];
    __shared__ int   rows_s[128];
    __shared__ float wts[128];
    __shared__ float b1s[H_DIM], b2s[H_DIM], b3s[O_DIM];

    bf16* AbP = (bf16*)smem;              // phase1 A
    bf16* BbP = (bf16*)(smem + 32768);    // phase1 B

    int t = threadIdx.x, w = t >> 6, l = t & 63;
    if (t < 128) {
        int rr = (t < mcnt) ? t : (mcnt - 1);
        rows_s[t] = rowlist[e * B_ROWS + t0 + rr];
        wts[t]    = wlist[e * B_ROWS + t0 + rr];
    } else if (t < 256) {
        b1s[t - 128] = b1[e * H_DIM + (t - 128)];
    } else if (t < 384) {
        b2s[t - 256] = b2[e * H_DIM + (t - 256)];
    } else if (t < 384 + O_DIM) {
        b3s[t - 384] = b3[e * O_DIM + (t - 384)];
    }
    __syncthreads();

    const bf16* w1base = w1t + (size_t)e * H_DIM * D_DIM;
    // staging geometry: wave w fills segments 2w,2w+1 (1KB each) of A and B.
    // seg s, lane l -> row s*8 + (l>>3), block-in-row = l&7, source chunk
    // = (l&7) ^ ((l>>3)&7)  (XOR pre-swizzle; 8-lane group = one row's 128B)
    int sub = l >> 3;
    int blk = (l & 7) ^ sub;
    const bf16* aP0 = xb + (size_t)rows_s[w * 16 + sub]     * D_DIM + blk * 8;
    const bf16* aP1 = xb + (size_t)rows_s[w * 16 + 8 + sub] * D_DIM + blk * 8;
    const bf16* bP0 = w1base + (size_t)(w * 16 + sub)     * D_DIM + blk * 8;
    const bf16* bP1 = w1base + (size_t)(w * 16 + 8 + sub) * D_DIM + blk * 8;
    bf16* ldsA0 = AbP + (2 * w) * 512, *ldsA1 = AbP + (2 * w + 1) * 512;
    bf16* ldsB0 = BbP + (2 * w) * 512, *ldsB1 = BbP + (2 * w + 1) * 512;

    auto stage = [&](int bs, int kb) {
        int k0 = kb * 64;
        int boff = bs * 128 * 64;
        async_load16(aP0 + k0, ldsA0 + boff);
        async_load16(aP1 + k0, ldsA1 + boff);
        async_load16(bP0 + k0, ldsB0 + boff);
        async_load16(bP1 + k0, ldsB1 + boff);
    };

    int wr = w & 3, wc = w >> 2;                 // wave tile: rows wr*32, cols wc*64
    floatx4 acc[2][4];
#pragma unroll
    for (int mi = 0; mi < 2; mi++)
#pragma unroll
        for (int ni = 0; ni < 4; ni++) acc[mi][ni] = (floatx4){0.f, 0.f, 0.f, 0.f};

    stage(0, 0);

    const int NKB = D_DIM / 64;   // 48
    for (int kb = 0; kb < NKB; kb++) {
        int bs = kb & 1;
        __syncthreads();                          // drains stage(bs); prev reads done
        if (kb + 1 < NKB) stage(bs ^ 1, kb + 1);  // in flight across MFMA phase
#pragma unroll
        for (int kc8 = 0; kc8 < 8; kc8 += 4) {
            int c = kc8 + (l >> 4);
            int swz = (c ^ (l & 7)) * 8;          // R&7 == C&7 == l&7
            short8 af[2], bfr[4];
#pragma unroll
            for (int mi = 0; mi < 2; mi++) {
                int R = wr * 32 + mi * 16 + (l & 15);
                af[mi] = *(const short8*)&AbP[bs * 8192 + R * 64 + swz];
            }
#pragma unroll
            for (int ni = 0; ni < 4; ni++) {
                int C = wc * 64 + ni * 16 + (l & 15);
                bfr[ni] = *(const short8*)&BbP[bs * 8192 + C * 64 + swz];
            }
#pragma unroll
            for (int mi = 0; mi < 2; mi++)
#pragma unroll
                for (int ni = 0; ni < 4; ni++)
                    acc[mi][ni] = __builtin_amdgcn_mfma_f32_16x16x32_bf16(
                        af[mi], bfr[ni], acc[mi][ni], 0, 0, 0);
        }
    }
    __syncthreads();   // all phase-1 LDS reads done; no loads pending -> reuse

    // ---- phase 2: h1 tile -> LDS, stage w2/w3, h2 GEMM, y GEMM, scatter ----
    bf16* h1s  = (bf16*)smem;             // [128][136]  (reused later as h2s)
    bf16* w2s  = (bf16*)(smem + 34816);   // [128][136]
    bf16* w3ts = (bf16*)(smem + 69632);   // [16][136]

    // h1 = relu(acc + b1): write each wave's 32x64 tile into LDS
    // (D row = (l>>4)*4 + reg, col = l&15; rows >= mcnt are dup-valid)
#pragma unroll
    for (int mi = 0; mi < 2; mi++)
#pragma unroll
        for (int r = 0; r < 4; r++) {
            int row = wr * 32 + mi * 16 + (l >> 4) * 4 + r;
#pragma unroll
            for (int ni = 0; ni < 4; ni++) {
                int col = wc * 64 + ni * 16 + (l & 15);
                h1s[row * 136 + col] =
                    __float2bfloat16(fmaxf(acc[mi][ni][r] + b1s[col], 0.0f));
            }
        }

    // stage w2 (128x128 bf16) and transposed zero-padded w3 (16x128)
    {
        const bf16* w2base = w2t + (size_t)e * H_DIM * H_DIM;
#pragma unroll
        for (int k = 0; k < 4; k++) {
            int si = t + 512 * k;                   // 0..2047 chunks of 16B
            *(uint4*)&w2s[(si >> 4) * 136 + (si & 15) * 8] =
                *(const uint4*)(w2base + (size_t)(si >> 4) * H_DIM + (si & 15) * 8);
        }
        for (int idx = t; idx < H_DIM * O_DIM; idx += 512)
            w3ts[(idx % 10) * 136 + idx / 10] =
                __float2bfloat16(w3[(size_t)e * H_DIM * O_DIM + idx]);
        for (int idx = t; idx < 6 * 128; idx += 512)
            w3ts[(10 + idx / 128) * 136 + (idx % 128)] = __float2bfloat16(0.0f);
    }
    __syncthreads();

    // h2 = relu(h1 @ w2 + b2), 8 waves, wave-tile 32x64, K=128
    int mb = wr * 32, nb = wc * 64;
    floatx4 acc2[2][4];
#pragma unroll
    for (int mi = 0; mi < 2; mi++)
#pragma unroll
        for (int ni = 0; ni < 4; ni++) acc2[mi][ni] = (floatx4){0.f, 0.f, 0.f, 0.f};
#pragma unroll
    for (int kc = 0; kc < 128; kc += 32) {
        short8 af[2], bfr[4];
#pragma unroll
        for (int mi = 0; mi < 2; mi++)
            af[mi] = *(const short8*)&h1s[(mb + mi * 16 + (l & 15)) * 136 + kc + (l >> 4) * 8];
#pragma unroll
        for (int ni = 0; ni < 4; ni++)
            bfr[ni] = *(const short8*)&w2s[(nb + ni * 16 + (l & 15)) * 136 + kc + (l >> 4) * 8];
#pragma unroll
        for (int mi = 0; mi < 2; mi++)
#pragma unroll
            for (int ni = 0; ni < 4; ni++)
                acc2[mi][ni] = __builtin_amdgcn_mfma_f32_16x16x32_bf16(
                    af[mi], bfr[ni], acc2[mi][ni], 0, 0, 0);
    }
    __syncthreads();   // all reads of h1s done; reuse as h2s

    bf16* h2s = h1s;
#pragma unroll
    for (int mi = 0; mi < 2; mi++)
#pragma unroll
        for (int r = 0; r < 4; r++) {
            int row = mb + mi * 16 + (l >> 4) * 4 + r;
#pragma unroll
            for (int ni = 0; ni < 4; ni++) {
                int col = nb + ni * 16 + (l & 15);
                h2s[row * 136 + col] =
                    __float2bfloat16(fmaxf(acc2[mi][ni][r] + b2s[col], 0.0f));
            }
        }
    __syncthreads();

    // y tile via MFMA (wave w -> rows w*16..w*16+15), K=128
    floatx4 acc3 = (floatx4){0.f, 0.f, 0.f, 0.f};
    int m3 = w * 16;
#pragma unroll
    for (int kc = 0; kc < 128; kc += 32) {
        short8 af  = *(const short8*)&h2s[(m3 + (l & 15)) * 136 + kc + (l >> 4) * 8];
        short8 bf3 = *(const short8*)&w3ts[(l & 15) * 136 + kc + (l >> 4) * 8];
        acc3 = __builtin_amdgcn_mfma_f32_16x16x32_bf16(af, bf3, acc3, 0, 0, 0);
    }
    int col = l & 15;
    if (col < O_DIM) {
#pragma unroll
        for (int r = 0; r < 4; r++) {
            int row = m3 + (l >> 4) * 4 + r;
            if (row < mcnt)
                atomicAdd(&y[(size_t)rows_s[row] * O_DIM + col],
                          wts[row] * (acc3[r] + b3s[col]));
        }
    }
}

// ---------------------------------------------------------------------------
extern "C" void kernel_launch(void* const* d_in, const int* in_sizes, int n_in,
                              void* d_out, int out_size, void* d_ws, size_t ws_size,
                              hipStream_t stream) {
    (void)in_sizes; (void)n_in; (void)ws_size;
    const float* x      = (const float*)d_in[0];
    const float* gate_w = (const float*)d_in[1];
    const float* gate_b = (const float*)d_in[2];
    const float* w1     = (const float*)d_in[3];
    const float* b1     = (const float*)d_in[4];
    const float* w2     = (const float*)d_in[5];
    const float* b2     = (const float*)d_in[6];
    const float* w3     = (const float*)d_in[7];
    const float* b3     = (const float*)d_in[8];
    float* y = (float*)d_out;

    char* ws = (char*)d_ws;
    size_t off = 0;
    auto alloc = [&](size_t bytes) {
        void* p = ws + off;
        off = (off + bytes + 255) & ~(size_t)255;
        return p;
    };
    bf16*  x_bf16  = (bf16*)alloc((size_t)B_ROWS * D_DIM * 2);            // 100.7 MB
    bf16*  w1t     = (bf16*)alloc((size_t)E_NUM * H_DIM * D_DIM * 2);     // 6.3 MB
    bf16*  w2t     = (bf16*)alloc((size_t)E_NUM * H_DIM * H_DIM * 2);     // 0.26 MB
    float* gwr     = (float*)alloc((size_t)D_DIM * E_NUM * 4);            // 393 KB
    int*   rowlist = (int*)alloc((size_t)E_NUM * B_ROWS * 4);
    float* wlist   = (float*)alloc((size_t)E_NUM * B_ROWS * 4);
    int*   gcnt    = (int*)alloc(64);

    hipMemsetAsync(d_out, 0, (size_t)out_size * sizeof(float), stream);
    hipMemsetAsync(gcnt, 0, 64, stream);

    gate_w_reorder_kernel<<<D_DIM * E_NUM / 4 / 256, 256, 0, stream>>>(gate_w, gwr);
    transpose_bf16_kernel<<<dim3(D_DIM / 32, H_DIM / 32, E_NUM), dim3(32, 8), 0, stream>>>(
        w1, w1t, D_DIM, H_DIM);
    transpose_bf16_kernel<<<dim3(H_DIM / 32, H_DIM / 32, E_NUM), dim3(32, 8), 0, stream>>>(
        w2, w2t, H_DIM, H_DIM);
    gate_kernel<<<B_ROWS / 8, 256, 0, stream>>>(x, gwr, gate_b, x_bf16,
                                                rowlist, wlist, gcnt);
    moe_fused_kernel<<<(B_ROWS / 128) * E_NUM, 512, 0, stream>>>(
        x_bf16, w1t, b1, w2t, b2, w3, b3, rowlist, wlist, gcnt, y);
}